// Round 3
// baseline (791.852 us; speedup 1.0000x reference)
//
#include <hip/hip_runtime.h>
#include <hip/hip_bf16.h>

// PWC-Net correlation: out[b, dy*9+dx, y, x] =
//   (1/C) * sum_c first[b,c,y,x] * second[b,c, y+dy-4, x+dx-4]  (zero-padded)
// B=8, C=128, H=W=128.
//
// Round 3: dy split across blocks (3 dy-groups), 192-thread blocks (3 waves,
// wave = one dy of the group). LDS 25.6 KiB -> 6 blocks/CU, grid 1536.
// A dy-group needs only 4 second-rows: ys = y0+d0-4+rr, rr in [0,4).
// All staging coordinates are chunk-invariant (computed once); per chunk the
// global pointer just advances by CC*H*W. Invalid slots (pad cols / OOB rows)
// write zeros every chunk. Register double-buffer pipeline, 1 barrier/chunk.

#define B  8
#define C  128
#define H  128
#define W  128
#define CC 4
#define YB 2
#define NTHR 192
#define NCHUNK (C / CC)        // 32
#define SROWS 4                // second rows per dy-group
#define SW    136              // padded row: x = -4 .. 131
#define NSEC4 (CC * SROWS * (SW / 4))   // 544 float4 slots
#define NFIR4 (CC * YB * (W / 4))       // 256 float4 slots
#define CHSTRIDE (CC * H * W)           // 65536 floats per chunk step

__global__ __launch_bounds__(NTHR, 5)
void ModuleCorrelation_41970420416706_kernel(const float* __restrict__ first,
                                             const float* __restrict__ second,
                                             float* __restrict__ out) {
    __shared__ __align__(16) float sFirst[2][CC][YB][W];       // 8 KiB
    __shared__ __align__(16) float sSec[2][CC][SROWS][SW];     // 17 KiB

    const int bx  = blockIdx.x;
    const int b   = bx / 192;
    const int rem = bx - b * 192;
    const int y0  = (rem / 3) * YB;
    const int dg  = rem - (rem / 3) * 3;
    const int d0  = dg * 3;                  // dy group base: 0, 3, 6

    const int t    = threadIdx.x;
    const int w    = t >> 6;                 // wave = dy - d0, in [0,3)
    const int lane = t & 63;
    const int yi   = lane >> 5;
    const int x0   = (lane & 31) * 4;

    const float* firstB  = first  + (size_t)b * C * H * W;
    const float* secondB = second + (size_t)b * C * H * W;

    // ---- chunk-invariant staging coordinates ----
    const float* gS[3]; int lS[3]; bool hS[3];
#pragma unroll
    for (int i = 0; i < 3; ++i) {
        const int idx = t + i * NTHR;
        hS[i] = (idx < NSEC4);
        const int c  = idx / (SROWS * (SW / 4));            // /136
        const int r2 = idx - c * (SROWS * (SW / 4));
        const int rr = r2 / (SW / 4);                       // /34
        const int q  = r2 - rr * (SW / 4);
        const int ys = y0 + d0 - 4 + rr;
        const bool ld = hS[i] && (q >= 1) && (q <= 32) && (ys >= 0) && (ys < H);
        gS[i] = ld ? (secondB + (c * H + ys) * W + (q * 4 - 4)) : nullptr;
        lS[i] = (c * SROWS + rr) * SW + q * 4;
    }
    const float* gF[2]; int lF[2]; bool hF[2];
#pragma unroll
    for (int j = 0; j < 2; ++j) {
        const int idx = t + j * NTHR;
        hF[j] = (idx < NFIR4);
        const int c  = idx >> 6;            // /(YB*W/4)=64
        const int yy = (idx >> 5) & 1;
        const int q  = idx & 31;
        gF[j] = firstB + (c * H + y0 + yy) * W + q * 4;
        lF[j] = (c * YB + yy) * W + q * 4;
    }

    float4 rS[3], rF[2];
    const float4 z4 = make_float4(0.f, 0.f, 0.f, 0.f);

    auto issueLoads = [&](int chunk) {
        const int off = chunk * CHSTRIDE;
#pragma unroll
        for (int i = 0; i < 3; ++i)
            rS[i] = gS[i] ? *(const float4*)(gS[i] + off) : z4;
#pragma unroll
        for (int j = 0; j < 2; ++j)
            if (hF[j]) rF[j] = *(const float4*)(gF[j] + off);
    };
    auto writeLDS = [&](int buf) {
        float* sS = &sSec[buf][0][0][0];
        float* sF = &sFirst[buf][0][0][0];
#pragma unroll
        for (int i = 0; i < 3; ++i)
            if (hS[i]) *(float4*)(sS + lS[i]) = rS[i];
#pragma unroll
        for (int j = 0; j < 2; ++j)
            if (hF[j]) *(float4*)(sF + lF[j]) = rF[j];
    };

    float acc[9][4];
#pragma unroll
    for (int dx = 0; dx < 9; ++dx)
#pragma unroll
        for (int j = 0; j < 4; ++j) acc[dx][j] = 0.f;

    // ---- prologue ----
    issueLoads(0);
    writeLDS(0);
    issueLoads(1);
    __syncthreads();

    // ---- main pipeline: one barrier per chunk ----
    for (int k = 0; k < NCHUNK; ++k) {
        const int buf = k & 1;
        const float* sF = &sFirst[buf][0][0][0];
        const float* sS = &sSec[buf][0][0][0];

#pragma unroll
        for (int c = 0; c < CC; ++c) {
            const float4 f = *(const float4*)(sF + (c * YB + yi) * W + x0);
            const float* srow = sS + (c * SROWS + yi + w) * SW + x0;
            const float4 sa = *(const float4*)(srow);
            const float4 sb = *(const float4*)(srow + 4);
            const float4 sc = *(const float4*)(srow + 8);
            const float s[12] = {sa.x, sa.y, sa.z, sa.w,
                                 sb.x, sb.y, sb.z, sb.w,
                                 sc.x, sc.y, sc.z, sc.w};
#pragma unroll
            for (int dx = 0; dx < 9; ++dx) {
                acc[dx][0] += f.x * s[dx + 0];
                acc[dx][1] += f.y * s[dx + 1];
                acc[dx][2] += f.z * s[dx + 2];
                acc[dx][3] += f.w * s[dx + 3];
            }
        }

        if (k + 1 < NCHUNK) {
            writeLDS(buf ^ 1);
            if (k + 2 < NCHUNK) issueLoads(k + 2);
        }
        __syncthreads();
    }

    // ---- epilogue ----
    const float scale = 1.0f / (float)C;
    const int dy = d0 + w;
    const int yOut = y0 + yi;
#pragma unroll
    for (int dx = 0; dx < 9; ++dx) {
        const int tc = dy * 9 + dx;
        float4 o;
        o.x = acc[dx][0] * scale;
        o.y = acc[dx][1] * scale;
        o.z = acc[dx][2] * scale;
        o.w = acc[dx][3] * scale;
        *(float4*)&out[((b * 81 + tc) * H + yOut) * W + x0] = o;
    }
}

extern "C" void kernel_launch(void* const* d_in, const int* in_sizes, int n_in,
                              void* d_out, int out_size, void* d_ws, size_t ws_size,
                              hipStream_t stream) {
    const float* first  = (const float*)d_in[0];
    const float* second = (const float*)d_in[1];
    float* out = (float*)d_out;

    dim3 grid(B * (H / YB) * 3);   // 1536 blocks (6 per CU)
    dim3 block(NTHR);              // 192 threads = 3 waves
    ModuleCorrelation_41970420416706_kernel<<<grid, block, 0, stream>>>(first, second, out);
}

// Round 4
// 464.678 us; speedup vs baseline: 1.7041x; 1.7041x over previous
//
#include <hip/hip_runtime.h>
#include <hip/hip_bf16.h>

// PWC-Net correlation: out[b, dy*9+dx, y, x] =
//   (1/C) * sum_c first[b,c,y,x] * second[b,c, y+dy-4, x+dx-4]  (zero-padded)
// B=8, C=128, H=W=128.
//
// Round 4: Round-3 structure (dy split into 3 groups, 192-thread blocks,
// 25.6 KiB double-buffered LDS, chunk-invariant staging, 1 barrier/chunk)
// with the register cap FIXED: launch_bounds(192,2) -> ~128 VGPR cap, no
// scratch spill (R3's (192,5) capped at 48 VGPRs and spilled ~1 GB/dispatch).
// Staging addresses stored as int offsets (sign bit = invalid) to trim VGPRs.

#define B  8
#define C  128
#define H  128
#define W  128
#define CC 4
#define YB 2
#define NTHR 192
#define NCHUNK (C / CC)        // 32
#define SROWS 4                // second rows per dy-group
#define SW    136              // padded row: x = -4 .. 131
#define NSEC4 (CC * SROWS * (SW / 4))   // 544 float4 slots
#define NFIR4 (CC * YB * (W / 4))       // 256 float4 slots
#define CHSTRIDE (CC * H * W)           // 65536 floats per chunk step

__global__ __launch_bounds__(NTHR, 2)
void ModuleCorrelation_41970420416706_kernel(const float* __restrict__ first,
                                             const float* __restrict__ second,
                                             float* __restrict__ out) {
    __shared__ __align__(16) float sFirst[2][CC][YB][W];       // 8 KiB
    __shared__ __align__(16) float sSec[2][CC][SROWS][SW];     // 17 KiB

    const int bx  = blockIdx.x;
    const int b   = bx / 192;
    const int rem = bx - b * 192;
    const int y0  = (rem / 3) * YB;
    const int dg  = rem - (rem / 3) * 3;
    const int d0  = dg * 3;                  // dy group base: 0, 3, 6

    const int t    = threadIdx.x;
    const int w    = t >> 6;                 // wave = dy - d0, in [0,3)
    const int lane = t & 63;
    const int yi   = lane >> 5;
    const int x0   = (lane & 31) * 4;

    const float* firstB  = first  + (size_t)b * C * H * W;
    const float* secondB = second + (size_t)b * C * H * W;

    // ---- chunk-invariant staging coordinates (int offsets, -1 = zero) ----
    int oS[3], lS[3];
#pragma unroll
    for (int i = 0; i < 3; ++i) {
        const int idx = t + i * NTHR;
        const bool has = (idx < NSEC4);
        const int c  = idx / (SROWS * (SW / 4));            // /136
        const int r2 = idx - c * (SROWS * (SW / 4));
        const int rr = r2 / (SW / 4);                       // /34
        const int q  = r2 - rr * (SW / 4);
        const int ys = y0 + d0 - 4 + rr;
        const bool ld = has && (q >= 1) && (q <= 32) && (ys >= 0) && (ys < H);
        oS[i] = ld ? ((c * H + ys) * W + (q * 4 - 4)) : -1;
        lS[i] = has ? ((c * SROWS + rr) * SW + q * 4) : -1;
    }
    int oF[2], lF[2];
#pragma unroll
    for (int j = 0; j < 2; ++j) {
        const int idx = t + j * NTHR;
        const bool has = (idx < NFIR4);
        const int c  = idx >> 6;            // /(YB*W/4)=64
        const int yy = (idx >> 5) & 1;
        const int q  = idx & 31;
        oF[j] = (c * H + y0 + yy) * W + q * 4;
        lF[j] = has ? ((c * YB + yy) * W + q * 4) : -1;
    }

    float4 rS[3], rF[2];
    const float4 z4 = make_float4(0.f, 0.f, 0.f, 0.f);

    auto issueLoads = [&](int chunk) {
        const int off = chunk * CHSTRIDE;
#pragma unroll
        for (int i = 0; i < 3; ++i)
            rS[i] = (oS[i] >= 0) ? *(const float4*)(secondB + oS[i] + off) : z4;
#pragma unroll
        for (int j = 0; j < 2; ++j)
            if (lF[j] >= 0) rF[j] = *(const float4*)(firstB + oF[j] + off);
    };
    auto writeLDS = [&](int buf) {
        float* sS = &sSec[buf][0][0][0];
        float* sF = &sFirst[buf][0][0][0];
#pragma unroll
        for (int i = 0; i < 3; ++i)
            if (lS[i] >= 0) *(float4*)(sS + lS[i]) = rS[i];
#pragma unroll
        for (int j = 0; j < 2; ++j)
            if (lF[j] >= 0) *(float4*)(sF + lF[j]) = rF[j];
    };

    float acc[9][4];
#pragma unroll
    for (int dx = 0; dx < 9; ++dx)
#pragma unroll
        for (int j = 0; j < 4; ++j) acc[dx][j] = 0.f;

    // ---- prologue ----
    issueLoads(0);
    writeLDS(0);
    issueLoads(1);
    __syncthreads();

    // ---- main pipeline: one barrier per chunk ----
    for (int k = 0; k < NCHUNK; ++k) {
        const int buf = k & 1;
        const float* sF = &sFirst[buf][0][0][0];
        const float* sS = &sSec[buf][0][0][0];

#pragma unroll
        for (int c = 0; c < CC; ++c) {
            const float4 f = *(const float4*)(sF + (c * YB + yi) * W + x0);
            const float* srow = sS + (c * SROWS + yi + w) * SW + x0;
            const float4 sa = *(const float4*)(srow);
            const float4 sb = *(const float4*)(srow + 4);
            const float4 sc = *(const float4*)(srow + 8);
            const float s[12] = {sa.x, sa.y, sa.z, sa.w,
                                 sb.x, sb.y, sb.z, sb.w,
                                 sc.x, sc.y, sc.z, sc.w};
#pragma unroll
            for (int dx = 0; dx < 9; ++dx) {
                acc[dx][0] += f.x * s[dx + 0];
                acc[dx][1] += f.y * s[dx + 1];
                acc[dx][2] += f.z * s[dx + 2];
                acc[dx][3] += f.w * s[dx + 3];
            }
        }

        if (k + 1 < NCHUNK) {
            writeLDS(buf ^ 1);
            if (k + 2 < NCHUNK) issueLoads(k + 2);
        }
        __syncthreads();
    }

    // ---- epilogue ----
    const float scale = 1.0f / (float)C;
    const int dy = d0 + w;
    const int yOut = y0 + yi;
#pragma unroll
    for (int dx = 0; dx < 9; ++dx) {
        const int tc = dy * 9 + dx;
        float4 o;
        o.x = acc[dx][0] * scale;
        o.y = acc[dx][1] * scale;
        o.z = acc[dx][2] * scale;
        o.w = acc[dx][3] * scale;
        *(float4*)&out[((b * 81 + tc) * H + yOut) * W + x0] = o;
    }
}

extern "C" void kernel_launch(void* const* d_in, const int* in_sizes, int n_in,
                              void* d_out, int out_size, void* d_ws, size_t ws_size,
                              hipStream_t stream) {
    const float* first  = (const float*)d_in[0];
    const float* second = (const float*)d_in[1];
    float* out = (float*)d_out;

    dim3 grid(B * (H / YB) * 3);   // 1536 blocks
    dim3 block(NTHR);              // 192 threads = 3 waves
    ModuleCorrelation_41970420416706_kernel<<<grid, block, 0, stream>>>(first, second, out);
}

// Round 5
// 211.872 us; speedup vs baseline: 3.7374x; 2.1932x over previous
//
#include <hip/hip_runtime.h>
#include <hip/hip_bf16.h>

// PWC-Net correlation: out[b, dy*9+dx, y, x] =
//   (1/C) * sum_c first[b,c,y,x] * second[b,c, y+dy-4, x+dx-4]  (zero-padded)
// B=8, C=128, H=W=128.
//
// Round 5: kill the register spill by deleting the register-prefetch stage.
// Global->LDS staging via __builtin_amdgcn_global_load_lds (async DMA, no
// VGPR round trip). LDS rows are UNPADDED (DMA dest = wave-uniform base +
// lane*16); x-edge zeros handled by 2 cndmask4 in compute; y-OOB rows
// pre-zeroed once (chunk-invariant) and skipped by DMA. 1 barrier/chunk:
// stage(k+1) -> compute(k) -> __syncthreads (drains vmcnt).
// LDS 24 KiB -> 6 blocks/CU; grid 1536 = exactly 6/CU.

#define B  8
#define C  128
#define H  128
#define W  128
#define CC 4
#define YB 2
#define NTHR 192
#define NCHUNK (C / CC)        // 32
#define SROWS 4                // second rows per dy-group
#define CHSTRIDE (CC * H * W)  // 65536 floats per chunk step

typedef const void __attribute__((address_space(1)))* gvp;
typedef void __attribute__((address_space(3)))* lvp;

__device__ __forceinline__ void dma16(const float* g, float* l) {
    __builtin_amdgcn_global_load_lds((gvp)g, (lvp)l, 16, 0, 0);
}

__global__ __launch_bounds__(NTHR) __attribute__((amdgpu_waves_per_eu(4)))
void ModuleCorrelation_41970420416706_kernel(const float* __restrict__ first,
                                             const float* __restrict__ second,
                                             float* __restrict__ out) {
    __shared__ __align__(16) float sFirst[2][CC][YB][W];     // 8 KiB
    __shared__ __align__(16) float sSec[2][CC][SROWS][W];    // 16 KiB

    const int bx  = blockIdx.x;
    const int b   = bx / 192;
    const int rem = bx - b * 192;
    const int y0  = (rem / 3) * YB;
    const int dg  = rem - (rem / 3) * 3;     // dg fastest: 3 sibling blocks share rows in L2
    const int d0  = dg * 3;                  // dy group base: 0, 3, 6

    const int t    = threadIdx.x;
    const int w    = t >> 6;                 // wave = dy - d0, in [0,3)
    const int lane = t & 63;
    const int yi   = lane >> 5;
    const int x0   = (lane & 31) * 4;

    const float* firstB  = first  + (size_t)b * C * H * W;
    const float* secondB = second + (size_t)b * C * H * W;

    // ---- pre-zero sSec rows whose source y is OOB (chunk-invariant) ----
    {
        const float4 z4 = make_float4(0.f, 0.f, 0.f, 0.f);
        float4* p = (float4*)&sSec[0][0][0][0];
        for (int idx = t; idx < 2 * CC * SROWS * (W / 4); idx += NTHR) {  // 1024
            const int r2 = idx & 511;
            const int rr = (r2 >> 5) & 3;
            const int ys = y0 + d0 - 4 + rr;
            if (ys < 0 || ys >= H) p[idx] = z4;
        }
    }

    // ---- async staging: 24 rows/chunk. wave2: first (4 full-wave 1KB DMAs);
    //      waves 0,1: second (8 half-wave 512B row DMAs each) ----
    auto stage = [&](int buf, int chunk) {
        const int off = chunk * CHSTRIDE;
        if (w == 2) {
#pragma unroll
            for (int c = 0; c < CC; ++c)   // rows y0,y0+1 contiguous in global+LDS
                dma16(firstB + off + (c * H + y0) * W + lane * 4,
                      &sFirst[buf][c][0][0]);
        } else if (lane < 32) {
#pragma unroll
            for (int i = 0; i < 8; ++i) {
                const int r  = w * 8 + i;            // 0..15
                const int c  = r >> 2;
                const int rr = r & 3;
                const int ys = y0 + d0 - 4 + rr;
                if (ys >= 0 && ys < H)               // wave-uniform
                    dma16(secondB + off + (c * H + ys) * W + lane * 4,
                          &sSec[buf][c][rr][0]);
            }
        }
    };

    float acc[9][4];
#pragma unroll
    for (int dx = 0; dx < 9; ++dx)
#pragma unroll
        for (int j = 0; j < 4; ++j) acc[dx][j] = 0.f;

    stage(0, 0);
    __syncthreads();                 // buf0 staged (vmcnt drained) + zeros visible

    const bool edgeL = (x0 == 0);
    const bool edgeR = (x0 == 124);
    const int offA = edgeL ? 0 : x0 - 4;     // clamped aligned read, masked below
    const int offC = edgeR ? x0 : x0 + 4;
    const int fOff = yi * W + x0;
    const int sOff = (yi + w) * W;           // rr = yi + w

    for (int k = 0; k < NCHUNK; ++k) {
        const int buf = k & 1;
        if (k + 1 < NCHUNK) stage(buf ^ 1, k + 1);   // lands during compute

        const float* sF = &sFirst[buf][0][0][0];
        const float* sS = &sSec[buf][0][0][0];
#pragma unroll
        for (int c = 0; c < CC; ++c) {
            const float4 f  = *(const float4*)(sF + c * (YB * W) + fOff);
            const float* sr = sS + c * (SROWS * W) + sOff;
            float4 A        = *(const float4*)(sr + offA);
            const float4 Bv = *(const float4*)(sr + x0);
            float4 Cv       = *(const float4*)(sr + offC);
            if (edgeL) { A.x = 0.f; A.y = 0.f; A.z = 0.f; A.w = 0.f; }
            if (edgeR) { Cv.x = 0.f; Cv.y = 0.f; Cv.z = 0.f; Cv.w = 0.f; }
            const float s[12] = {A.x,  A.y,  A.z,  A.w,
                                 Bv.x, Bv.y, Bv.z, Bv.w,
                                 Cv.x, Cv.y, Cv.z, Cv.w};
#pragma unroll
            for (int dx = 0; dx < 9; ++dx) {
                acc[dx][0] += f.x * s[dx + 0];
                acc[dx][1] += f.y * s[dx + 1];
                acc[dx][2] += f.z * s[dx + 2];
                acc[dx][3] += f.w * s[dx + 3];
            }
        }
        __syncthreads();   // all waves done with buf; stage(k+1) drained
    }

    // ---- epilogue ----
    const float scale = 1.0f / (float)C;
    const int dy = d0 + w;
    const int yOut = y0 + yi;
#pragma unroll
    for (int dx = 0; dx < 9; ++dx) {
        const int tc = dy * 9 + dx;
        float4 o;
        o.x = acc[dx][0] * scale;
        o.y = acc[dx][1] * scale;
        o.z = acc[dx][2] * scale;
        o.w = acc[dx][3] * scale;
        *(float4*)&out[((b * 81 + tc) * H + yOut) * W + x0] = o;
    }
}

extern "C" void kernel_launch(void* const* d_in, const int* in_sizes, int n_in,
                              void* d_out, int out_size, void* d_ws, size_t ws_size,
                              hipStream_t stream) {
    const float* first  = (const float*)d_in[0];
    const float* second = (const float*)d_in[1];
    float* out = (float*)d_out;

    dim3 grid(B * (H / YB) * 3);   // 1536 blocks = 6 per CU
    dim3 block(NTHR);              // 192 threads = 3 waves
    ModuleCorrelation_41970420416706_kernel<<<grid, block, 0, stream>>>(first, second, out);
}